// Round 16
// baseline (535.200 us; speedup 1.0000x reference)
//
#include <hip/hip_runtime.h>
#include <hip/hip_bf16.h>
#include <math.h>

#define NN 50000
#define EE 800000
#define DD 128
#define HH 8
#define DKK 16

typedef __attribute__((ext_vector_type(8))) short short8;
typedef __attribute__((ext_vector_type(4))) float f32x4;
typedef __attribute__((ext_vector_type(4))) unsigned short ushort4v;
typedef __attribute__((ext_vector_type(8))) unsigned short ushort8v;

static __device__ __forceinline__ unsigned short f2bf(float x) {
  __hip_bfloat16 h = __float2bfloat16(x);   // RNE
  return *reinterpret_cast<unsigned short*>(&h);
}
static __device__ __forceinline__ float bf2f(unsigned short u) {
  return __uint_as_float(((unsigned int)u) << 16);
}

// ---------------------------------------------------------------------------
// Bucket-by-dst prep: histogram -> scan (2 dispatches) -> perm fill.
// ---------------------------------------------------------------------------
__global__ __launch_bounds__(256) void hist_kernel(const int* __restrict__ dst,
                                                   int* __restrict__ cnt) {
  int i4 = blockIdx.x * 256 + threadIdx.x;
  if (i4 < EE / 4) {
    int4 d = *(const int4*)&dst[i4 * 4];
    atomicAdd(&cnt[d.x], 1);
    atomicAdd(&cnt[d.y], 1);
    atomicAdd(&cnt[d.z], 1);
    atomicAdd(&cnt[d.w], 1);
  }
}

#define SCAN_NB ((NN + 1023) / 1024)   // 49 chunks of 1024

__global__ __launch_bounds__(256) void scan1_kernel(const int* __restrict__ cnt,
                                                    int* __restrict__ bsum) {
  __shared__ int red[256];
  const int b = blockIdx.x, t = threadIdx.x;
  const int base = b * 1024 + t * 4;
  int s = 0;
  if (base + 3 < NN) {
    int4 v = *(const int4*)&cnt[base];
    s = v.x + v.y + v.z + v.w;
  } else {
    for (int j = 0; j < 4; ++j) if (base + j < NN) s += cnt[base + j];
  }
  red[t] = s;
  __syncthreads();
  for (int off = 1; off < 256; off <<= 1) {
    int v = (t >= off) ? red[t - off] : 0;
    __syncthreads();
    red[t] += v;
    __syncthreads();
  }
  if (t == 255) bsum[b] = red[255];
}

__global__ __launch_bounds__(256) void scan3_kernel(const int* __restrict__ cnt,
                                                    const int* __restrict__ bsum,
                                                    int* __restrict__ rowptr) {
  __shared__ int red[256];
  __shared__ int bs[SCAN_NB];
  const int b = blockIdx.x, t = threadIdx.x;
  if (t < SCAN_NB) bs[t] = bsum[t];
  const int base = b * 1024 + t * 4;
  int v0 = 0, v1 = 0, v2 = 0, v3 = 0;
  if (base + 3 < NN) {
    int4 v = *(const int4*)&cnt[base];
    v0 = v.x; v1 = v.y; v2 = v.z; v3 = v.w;
  } else {
    if (base + 0 < NN) v0 = cnt[base + 0];
    if (base + 1 < NN) v1 = cnt[base + 1];
    if (base + 2 < NN) v2 = cnt[base + 2];
    if (base + 3 < NN) v3 = cnt[base + 3];
  }
  red[t] = v0 + v1 + v2 + v3;
  __syncthreads();
  for (int off = 1; off < 256; off <<= 1) {
    int v = (t >= off) ? red[t - off] : 0;
    __syncthreads();
    red[t] += v;
    __syncthreads();
  }
  int bpre = 0;
  for (int j = 0; j < b; ++j) bpre += bs[j];
  int r = bpre + ((t == 0) ? 0 : red[t - 1]);
  if (base + 0 < NN) { rowptr[base + 0] = r; r += v0; }
  if (base + 1 < NN) { rowptr[base + 1] = r; r += v1; }
  if (base + 2 < NN) { rowptr[base + 2] = r; r += v2; }
  if (base + 3 < NN) { rowptr[base + 3] = r; }
}

__global__ __launch_bounds__(256) void fill_kernel(const int* __restrict__ dst,
                                                   const int* __restrict__ rowptr,
                                                   int* __restrict__ cur,
                                                   int* __restrict__ perm) {
  int i4 = blockIdx.x * 256 + threadIdx.x;
  if (i4 < EE / 4) {
    int4 dv = *(const int4*)&dst[i4 * 4];
    int d0 = dv.x, d1 = dv.y, d2 = dv.z, d3 = dv.w;
    int s0 = atomicAdd(&cur[d0], 1); perm[rowptr[d0] + s0] = i4 * 4 + 0;
    int s1 = atomicAdd(&cur[d1], 1); perm[rowptr[d1] + s1] = i4 * 4 + 1;
    int s2 = atomicAdd(&cur[d2], 1); perm[rowptr[d2] + s2] = i4 * 4 + 2;
    int s3 = atomicAdd(&cur[d3], 1); perm[rowptr[d3] + s3] = i4 * 4 + 3;
  }
}

// ---------------------------------------------------------------------------
// Prep: WT[j][c] = bf16(W[c][j])
// ---------------------------------------------------------------------------
__global__ void prep_w_kernel(const float* __restrict__ Wq,
                              const float* __restrict__ Wk,
                              const float* __restrict__ Wv,
                              unsigned short* __restrict__ WqT,
                              unsigned short* __restrict__ WkT,
                              unsigned short* __restrict__ WvT) {
  int c = blockIdx.x & 127;
  int m = blockIdx.x >> 7;
  int j = threadIdx.x;
  const float* W = (m == 0) ? Wq : (m == 1) ? Wk : Wv;
  unsigned short* o = (m == 0) ? WqT : (m == 1) ? WkT : WvT;
  o[j * DD + c] = f2bf(W[c * DD + j]);
}

// ---------------------------------------------------------------------------
// Kernel 1: node projections via MFMA + fused k->bf16 conversion.
// ---------------------------------------------------------------------------
__global__ __launch_bounds__(512) void node_proj_kernel(
    const float* __restrict__ q, const float* __restrict__ v,
    const float* __restrict__ k,
    const unsigned short* __restrict__ WqT, const unsigned short* __restrict__ WvT,
    unsigned short* __restrict__ Qh, unsigned short* __restrict__ Vh,
    unsigned short* __restrict__ kh)
{
  __shared__ __align__(16) unsigned short xl[64 * 136];
  const int tid = threadIdx.x;
  const int n0 = blockIdx.x * 64;

  #pragma unroll
  for (int p = 0; p < 2; ++p) {
    int f = p * 512 + tid;
    int i = f >> 4, c8 = f & 15;
    int n = n0 + i;
    if (n < NN) {
      float4 a = *(const float4*)&k[(size_t)n * DD + c8 * 8];
      float4 b = *(const float4*)&k[(size_t)n * DD + c8 * 8 + 4];
      ushort8v o = { f2bf(a.x), f2bf(a.y), f2bf(a.z), f2bf(a.w),
                     f2bf(b.x), f2bf(b.y), f2bf(b.z), f2bf(b.w) };
      *(ushort8v*)&kh[(size_t)n * DD + c8 * 8] = o;
    }
  }

  for (int m = 0; m < 2; ++m) {
    const float* x = m ? v : q;
    const unsigned short* WT = m ? WvT : WqT;
    unsigned short* o = m ? Vh : Qh;

    __syncthreads();
    #pragma unroll
    for (int p = 0; p < 4; ++p) {
      int f = p * 512 + tid;
      int i = f >> 5, c4 = f & 31;
      int n = n0 + i;
      float4 t = (n < NN) ? *(const float4*)&x[(size_t)n * DD + c4 * 4]
                          : float4{0.f, 0.f, 0.f, 0.f};
      ushort4v u = { f2bf(t.x), f2bf(t.y), f2bf(t.z), f2bf(t.w) };
      *(ushort4v*)&xl[i * 136 + c4 * 4] = u;
    }
    __syncthreads();

    const int lane = tid & 63, wid = tid >> 6;
    const int rg = wid & 3, cg = wid >> 2;
    const int lr = lane & 15, lg = lane >> 4;

    f32x4 acc0 = {0.f,0.f,0.f,0.f}, acc1 = {0.f,0.f,0.f,0.f};
    f32x4 acc2 = {0.f,0.f,0.f,0.f}, acc3 = {0.f,0.f,0.f,0.f};

    const unsigned short* Ab = &xl[(rg * 16 + lr) * 136];
    const unsigned short* B0 = &WT[(size_t)(cg * 64 +  0 + lr) * DD];
    const unsigned short* B1 = &WT[(size_t)(cg * 64 + 16 + lr) * DD];
    const unsigned short* B2 = &WT[(size_t)(cg * 64 + 32 + lr) * DD];
    const unsigned short* B3 = &WT[(size_t)(cg * 64 + 48 + lr) * DD];

    #pragma unroll
    for (int kk = 0; kk < 4; ++kk) {
      const int kof = kk * 32 + lg * 8;
      short8 a = *(const short8*)(Ab + kof);
      acc0 = __builtin_amdgcn_mfma_f32_16x16x32_bf16(a, *(const short8*)(B0 + kof), acc0, 0, 0, 0);
      acc1 = __builtin_amdgcn_mfma_f32_16x16x32_bf16(a, *(const short8*)(B1 + kof), acc1, 0, 0, 0);
      acc2 = __builtin_amdgcn_mfma_f32_16x16x32_bf16(a, *(const short8*)(B2 + kof), acc2, 0, 0, 0);
      acc3 = __builtin_amdgcn_mfma_f32_16x16x32_bf16(a, *(const short8*)(B3 + kof), acc3, 0, 0, 0);
    }

    const int r0 = rg * 16 + lg * 4;
    const int cb = cg * 64 + lr;
    #pragma unroll
    for (int r = 0; r < 4; ++r) {
      int n = n0 + r0 + r;
      if (n < NN) {
        unsigned short* orow = &o[(size_t)n * DD + cb];
        orow[ 0] = f2bf(acc0[r]);
        orow[16] = f2bf(acc1[r]);
        orow[32] = f2bf(acc2[r]);
        orow[48] = f2bf(acc3[r]);
      }
    }
  }
}

// ---------------------------------------------------------------------------
// Kernel 2: fused edge attention, 64 dst-sorted edges/block, 256 threads
// (4 waves x 16 edges end-to-end). NO LDS staging of kke: phase 1 gathers
// A-fragments DIRECTLY global->register (kh + e fused in-register; 12
// independent loads overlap 32 MFMAs — deep natural MLP). Ke -> padded buf;
// producer wave == consumer wave for Ke/P/He  =>  ZERO barriers after the
// index load. V read from global (L3-resident). LDS 21.2KB -> many small
// independent block-chains per CU (vs 2 big ones).
// Phase-1 math = r11 (verified); phase 2 + flush = r12 (verified).
// ---------------------------------------------------------------------------
__global__ __launch_bounds__(256) void edge_attn_kernel(
    const unsigned short* __restrict__ kh, const float* __restrict__ e,
    const int* __restrict__ src, const int* __restrict__ dst,
    const int* __restrict__ perm,
    const unsigned short* __restrict__ WkT,
    const unsigned short* __restrict__ Qh, const unsigned short* __restrict__ Vh,
    float* __restrict__ out)
{
  __shared__ __align__(16) unsigned short buf[64 * 136];     // 17408 B: Ke->He
  __shared__ __align__(16) unsigned short pbuf[4 * 16 * 24]; // 3072 B
  __shared__ int s_perm[64], s_src[64], s_dst[64];

  const int tid = threadIdx.x;
  const size_t e0 = (size_t)blockIdx.x * 64;
  const int lane = tid & 63, wid = tid >> 6;     // 4 waves
  const int lr = lane & 15, lg = lane >> 4;
  const int ebase = wid * 16;                    // this wave's 16 edges

  if (tid < 64) {
    int pe = perm[e0 + tid];
    s_perm[tid] = pe;
    s_src[tid] = src[pe];
    s_dst[tid] = dst[pe];
  }
  __syncthreads();   // the ONLY block barrier

  // ---- early-issue Q B-frags for this wave's 8 pairs ----
  const short8 zero8 = {0, 0, 0, 0, 0, 0, 0, 0};
  short8 qf[8];
  #pragma unroll
  for (int j = 0; j < 8; ++j) {
    if (lg < 2) {
      int ie = ebase + 2 * j + (lr >> 3);
      qf[j] = *(const short8*)&Qh[(size_t)s_dst[ie] * DD + (lr & 7) * DKK + lg * 8];
    } else qf[j] = zero8;
  }

  // ---- phase 1: Ke[16][128] = (kh[src]+e[perm]) @ Wk, A-frags from GLOBAL.
  // Lane (lr,lg): row = ebase+lr, k-cols kof..kof+8. 12 independent global
  // loads feed 32 MFMAs; no LDS staging, no barrier.
  {
    const int prow = s_perm[ebase + lr];
    const int srow = s_src[ebase + lr];
    const unsigned short* khp = &kh[(size_t)srow * DD];
    const float* ep = &e[(size_t)prow * DD];

    f32x4 acc[8];
    #pragma unroll
    for (int c = 0; c < 8; ++c) acc[c] = f32x4{0.f, 0.f, 0.f, 0.f};

    #pragma unroll
    for (int kk = 0; kk < 4; ++kk) {
      const int kof = kk * 32 + lg * 8;
      ushort8v kv = *(const ushort8v*)(khp + kof);
      float4 ea = *(const float4*)(ep + kof);
      float4 eb = *(const float4*)(ep + kof + 4);
      short8 af;
      af[0] = (short)f2bf(bf2f(kv[0]) + ea.x);
      af[1] = (short)f2bf(bf2f(kv[1]) + ea.y);
      af[2] = (short)f2bf(bf2f(kv[2]) + ea.z);
      af[3] = (short)f2bf(bf2f(kv[3]) + ea.w);
      af[4] = (short)f2bf(bf2f(kv[4]) + eb.x);
      af[5] = (short)f2bf(bf2f(kv[5]) + eb.y);
      af[6] = (short)f2bf(bf2f(kv[6]) + eb.z);
      af[7] = (short)f2bf(bf2f(kv[7]) + eb.w);
      #pragma unroll
      for (int c = 0; c < 8; ++c) {
        short8 bf = *(const short8*)&WkT[(size_t)(c * 16 + lr) * DD + kof];
        acc[c] = __builtin_amdgcn_mfma_f32_16x16x32_bf16(af, bf, acc[c], 0, 0, 0);
      }
    }
    // writeback (C layout: col=lane&15, row=(lane>>4)*4+r) — own rows only
    #pragma unroll
    for (int c = 0; c < 8; ++c)
      #pragma unroll
      for (int r = 0; r < 4; ++r)
        buf[(ebase + lg * 4 + r) * 136 + c * 16 + lr] = f2bf(acc[c][r]);
  }
  // no barrier: phase 2 reads only this wave's rows (same-wave LDS RAW)

  // ---- phase 2: 8 edge-pairs, all-MFMA, wave-local; V from global ----
  {
    const bool valid = ((lr < 8) == (lg < 2));
    unsigned short* pb = &pbuf[wid * 16 * 24];

    #pragma unroll
    for (int j = 0; j < 8; ++j) {
      const int iea = ebase + 2 * j, ieb = iea + 1;

      short8 af = zero8;
      if (lg < 2) {
        int ie = (lr < 8) ? iea : ieb;
        af = *(const short8*)&buf[ie * 136 + (lr & 7) * DKK + lg * 8];
      }
      f32x4 c = {0.f, 0.f, 0.f, 0.f};
      c = __builtin_amdgcn_mfma_f32_16x16x32_bf16(af, qf[j], c, 0, 0, 0);

      float s0, s1, s2, s3;
      {
        float x0 = c[0] * 0.25f, x1 = c[1] * 0.25f;
        float x2 = c[2] * 0.25f, x3 = c[3] * 0.25f;
        x0 = (x0 >= 0.f) ? x0 : 0.01f * x0;
        x1 = (x1 >= 0.f) ? x1 : 0.01f * x1;
        x2 = (x2 >= 0.f) ? x2 : 0.01f * x2;
        x3 = (x3 >= 0.f) ? x3 : 0.01f * x3;
        s0 = valid ? x0 : -1e30f;
        s1 = valid ? x1 : -1e30f;
        s2 = valid ? x2 : -1e30f;
        s3 = valid ? x3 : -1e30f;
      }
      float m = fmaxf(fmaxf(s0, s1), fmaxf(s2, s3));
      m = fmaxf(m, __shfl_xor(m, 16));
      m = fmaxf(m, __shfl_xor(m, 32));
      float p0 = __expf(s0 - m), p1 = __expf(s1 - m);
      float p2 = __expf(s2 - m), p3 = __expf(s3 - m);
      float su = p0 + p1 + p2 + p3;
      su += __shfl_xor(su, 16);
      su += __shfl_xor(su, 32);
      float rs = 1.0f / su;

      ushort4v pk = { f2bf(p0 * rs), f2bf(p1 * rs), f2bf(p2 * rs), f2bf(p3 * rs) };
      *(ushort4v*)&pb[lr * 24 + lg * 4] = pk;

      short8 pa = zero8;
      if (lg < 2) pa = *(const short8*)&pb[lr * 24 + lg * 8];
      short8 vf = zero8;
      if (lg < 2) {
        const unsigned short* vr = &Vh[(size_t)s_src[lg ? ieb : iea] * DD + lr];
        vf[0] = (short)vr[0 * 16];
        vf[1] = (short)vr[1 * 16];
        vf[2] = (short)vr[2 * 16];
        vf[3] = (short)vr[3 * 16];
        vf[4] = (short)vr[4 * 16];
        vf[5] = (short)vr[5 * 16];
        vf[6] = (short)vr[6 * 16];
        vf[7] = (short)vr[7 * 16];
      }
      f32x4 hc = {0.f, 0.f, 0.f, 0.f};
      hc = __builtin_amdgcn_mfma_f32_16x16x32_bf16(pa, vf, hc, 0, 0, 0);

      #pragma unroll
      for (int r = 0; r < 4; ++r) {
        int rr = lg * 4 + r;
        int ie = (rr < 8) ? iea : ieb;
        buf[ie * 136 + (rr & 7) * DKK + lr] = f2bf(hc[r]);
      }
    }
  }
  // no barrier: flush reads only this wave's rows

  // ---- wave-local flush: reduce own 16 edges over dst runs ----
  {
    const int d2 = lane;                 // col pair 2*d2, 2*d2+1
    float s0 = 0.0f, s1 = 0.0f;
    int curd = s_dst[ebase];
    #pragma unroll 8
    for (int j = 0; j < 16; ++j) {
      int i2 = ebase + j;
      int dn2 = s_dst[i2];
      if (dn2 != curd) {
        atomicAdd(&out[(size_t)curd * DD + d2 * 2],     s0);
        atomicAdd(&out[(size_t)curd * DD + d2 * 2 + 1], s1);
        s0 = 0.0f; s1 = 0.0f;
        curd = dn2;
      }
      unsigned int w = *(const unsigned int*)&buf[i2 * 136 + d2 * 2];
      s0 += bf2f((unsigned short)(w & 0xffff));
      s1 += bf2f((unsigned short)(w >> 16));
    }
    atomicAdd(&out[(size_t)curd * DD + d2 * 2],     s0);
    atomicAdd(&out[(size_t)curd * DD + d2 * 2 + 1], s1);
  }
}

// ---------------------------------------------------------------------------
extern "C" void kernel_launch(void* const* d_in, const int* in_sizes, int n_in,
                              void* d_out, int out_size, void* d_ws, size_t ws_size,
                              hipStream_t stream) {
  const float* q  = (const float*)d_in[0];
  const float* k  = (const float*)d_in[1];
  const float* v  = (const float*)d_in[2];
  const float* e  = (const float*)d_in[3];
  const int*   src = (const int*)d_in[4];
  const int*   dst = (const int*)d_in[5];
  const float* Wq = (const float*)d_in[6];
  const float* Wk = (const float*)d_in[7];
  const float* Wv = (const float*)d_in[8];

  float* out = (float*)d_out;
  char* wsb = (char*)d_ws;
  unsigned short* Qh  = (unsigned short*)wsb;                      // 12.8 MB
  unsigned short* Vh  = Qh + (size_t)NN * DD;                      // 12.8 MB
  unsigned short* kh  = Vh + (size_t)NN * DD;                      // 12.8 MB
  unsigned short* WqT = kh + (size_t)NN * DD;                      // 32 KB each
  unsigned short* WkT = WqT + DD * DD;
  unsigned short* WvT = WkT + DD * DD;
  int* cnt    = (int*)(WvT + DD * DD);                             // [NN]
  int* cur    = cnt + NN;                                          // [NN]
  int* rowptr = cur + NN;                                          // [NN+1]
  int* bsum   = rowptr + NN + 1;                                   // [64]
  int* perm   = bsum + 64;                                         // [EE]

  hipMemsetAsync(d_out, 0, (size_t)NN * DD * sizeof(float), stream);
  hipMemsetAsync(cnt, 0, 2 * NN * sizeof(int), stream);            // cnt + cur

  hist_kernel <<<(EE / 4 + 255) / 256, 256, 0, stream>>>(dst, cnt);
  scan1_kernel<<<SCAN_NB, 256, 0, stream>>>(cnt, bsum);
  scan3_kernel<<<SCAN_NB, 256, 0, stream>>>(cnt, bsum, rowptr);
  fill_kernel <<<(EE / 4 + 255) / 256, 256, 0, stream>>>(dst, rowptr, cur, perm);

  prep_w_kernel<<<3 * DD, DD, 0, stream>>>(Wq, Wk, Wv, WqT, WkT, WvT);
  node_proj_kernel<<<(NN + 63) / 64, 512, 0, stream>>>(q, v, k, WqT, WvT,
                                                       Qh, Vh, kh);
  edge_attn_kernel<<<EE / 64, 256, 0, stream>>>(kh, e, src, dst, perm,
                                                WkT, Qh, Vh, out);
}

// Round 17
// 381.133 us; speedup vs baseline: 1.4042x; 1.4042x over previous
//
#include <hip/hip_runtime.h>
#include <hip/hip_bf16.h>
#include <math.h>

#define NN 50000
#define EE 800000
#define DD 128
#define HH 8
#define DKK 16

typedef __attribute__((ext_vector_type(8))) short short8;
typedef __attribute__((ext_vector_type(4))) float f32x4;
typedef __attribute__((ext_vector_type(4))) unsigned short ushort4v;
typedef __attribute__((ext_vector_type(8))) unsigned short ushort8v;

static __device__ __forceinline__ unsigned short f2bf(float x) {
  __hip_bfloat16 h = __float2bfloat16(x);   // RNE
  return *reinterpret_cast<unsigned short*>(&h);
}
static __device__ __forceinline__ float bf2f(unsigned short u) {
  return __uint_as_float(((unsigned int)u) << 16);
}

// ---------------------------------------------------------------------------
// Bucket-by-dst prep: histogram -> scan (2 dispatches) -> perm fill.
// ---------------------------------------------------------------------------
__global__ __launch_bounds__(256) void hist_kernel(const int* __restrict__ dst,
                                                   int* __restrict__ cnt) {
  int i4 = blockIdx.x * 256 + threadIdx.x;
  if (i4 < EE / 4) {
    int4 d = *(const int4*)&dst[i4 * 4];
    atomicAdd(&cnt[d.x], 1);
    atomicAdd(&cnt[d.y], 1);
    atomicAdd(&cnt[d.z], 1);
    atomicAdd(&cnt[d.w], 1);
  }
}

#define SCAN_NB ((NN + 1023) / 1024)   // 49 chunks of 1024

__global__ __launch_bounds__(256) void scan1_kernel(const int* __restrict__ cnt,
                                                    int* __restrict__ bsum) {
  __shared__ int red[256];
  const int b = blockIdx.x, t = threadIdx.x;
  const int base = b * 1024 + t * 4;
  int s = 0;
  if (base + 3 < NN) {
    int4 v = *(const int4*)&cnt[base];
    s = v.x + v.y + v.z + v.w;
  } else {
    for (int j = 0; j < 4; ++j) if (base + j < NN) s += cnt[base + j];
  }
  red[t] = s;
  __syncthreads();
  for (int off = 1; off < 256; off <<= 1) {
    int v = (t >= off) ? red[t - off] : 0;
    __syncthreads();
    red[t] += v;
    __syncthreads();
  }
  if (t == 255) bsum[b] = red[255];
}

// scan3 with inlined scan of the 49 block sums (scan2 dispatch removed)
__global__ __launch_bounds__(256) void scan3_kernel(const int* __restrict__ cnt,
                                                    const int* __restrict__ bsum,
                                                    int* __restrict__ rowptr) {
  __shared__ int red[256];
  __shared__ int bs[SCAN_NB];
  const int b = blockIdx.x, t = threadIdx.x;
  if (t < SCAN_NB) bs[t] = bsum[t];
  const int base = b * 1024 + t * 4;
  int v0 = 0, v1 = 0, v2 = 0, v3 = 0;
  if (base + 3 < NN) {
    int4 v = *(const int4*)&cnt[base];
    v0 = v.x; v1 = v.y; v2 = v.z; v3 = v.w;
  } else {
    if (base + 0 < NN) v0 = cnt[base + 0];
    if (base + 1 < NN) v1 = cnt[base + 1];
    if (base + 2 < NN) v2 = cnt[base + 2];
    if (base + 3 < NN) v3 = cnt[base + 3];
  }
  red[t] = v0 + v1 + v2 + v3;
  __syncthreads();
  for (int off = 1; off < 256; off <<= 1) {
    int v = (t >= off) ? red[t - off] : 0;
    __syncthreads();
    red[t] += v;
    __syncthreads();
  }
  int bpre = 0;
  for (int j = 0; j < b; ++j) bpre += bs[j];     // b <= 48, LDS-resident
  int r = bpre + ((t == 0) ? 0 : red[t - 1]);    // exclusive within chunk
  if (base + 0 < NN) { rowptr[base + 0] = r; r += v0; }
  if (base + 1 < NN) { rowptr[base + 1] = r; r += v1; }
  if (base + 2 < NN) { rowptr[base + 2] = r; r += v2; }
  if (base + 3 < NN) { rowptr[base + 3] = r; }
}

__global__ __launch_bounds__(256) void fill_kernel(const int* __restrict__ dst,
                                                   const int* __restrict__ rowptr,
                                                   int* __restrict__ cur,
                                                   int* __restrict__ perm) {
  int i4 = blockIdx.x * 256 + threadIdx.x;
  if (i4 < EE / 4) {
    int4 dv = *(const int4*)&dst[i4 * 4];
    int d0 = dv.x, d1 = dv.y, d2 = dv.z, d3 = dv.w;
    int s0 = atomicAdd(&cur[d0], 1); perm[rowptr[d0] + s0] = i4 * 4 + 0;
    int s1 = atomicAdd(&cur[d1], 1); perm[rowptr[d1] + s1] = i4 * 4 + 1;
    int s2 = atomicAdd(&cur[d2], 1); perm[rowptr[d2] + s2] = i4 * 4 + 2;
    int s3 = atomicAdd(&cur[d3], 1); perm[rowptr[d3] + s3] = i4 * 4 + 3;
  }
}

// ---------------------------------------------------------------------------
// Prep: WT[j][c] = bf16(W[c][j])
// ---------------------------------------------------------------------------
__global__ void prep_w_kernel(const float* __restrict__ Wq,
                              const float* __restrict__ Wk,
                              const float* __restrict__ Wv,
                              unsigned short* __restrict__ WqT,
                              unsigned short* __restrict__ WkT,
                              unsigned short* __restrict__ WvT) {
  int c = blockIdx.x & 127;
  int m = blockIdx.x >> 7;
  int j = threadIdx.x;
  const float* W = (m == 0) ? Wq : (m == 1) ? Wk : Wv;
  unsigned short* o = (m == 0) ? WqT : (m == 1) ? WkT : WvT;
  o[j * DD + c] = f2bf(W[c * DD + j]);
}

// ---------------------------------------------------------------------------
// Kernel 1: node projections via MFMA + fused k->bf16 conversion.
// ---------------------------------------------------------------------------
__global__ __launch_bounds__(512) void node_proj_kernel(
    const float* __restrict__ q, const float* __restrict__ v,
    const float* __restrict__ k,
    const unsigned short* __restrict__ WqT, const unsigned short* __restrict__ WvT,
    unsigned short* __restrict__ Qh, unsigned short* __restrict__ Vh,
    unsigned short* __restrict__ kh)
{
  __shared__ __align__(16) unsigned short xl[64 * 136];
  const int tid = threadIdx.x;
  const int n0 = blockIdx.x * 64;

  #pragma unroll
  for (int p = 0; p < 2; ++p) {
    int f = p * 512 + tid;
    int i = f >> 4, c8 = f & 15;
    int n = n0 + i;
    if (n < NN) {
      float4 a = *(const float4*)&k[(size_t)n * DD + c8 * 8];
      float4 b = *(const float4*)&k[(size_t)n * DD + c8 * 8 + 4];
      ushort8v o = { f2bf(a.x), f2bf(a.y), f2bf(a.z), f2bf(a.w),
                     f2bf(b.x), f2bf(b.y), f2bf(b.z), f2bf(b.w) };
      *(ushort8v*)&kh[(size_t)n * DD + c8 * 8] = o;
    }
  }

  for (int m = 0; m < 2; ++m) {
    const float* x = m ? v : q;
    const unsigned short* WT = m ? WvT : WqT;
    unsigned short* o = m ? Vh : Qh;

    __syncthreads();
    #pragma unroll
    for (int p = 0; p < 4; ++p) {
      int f = p * 512 + tid;
      int i = f >> 5, c4 = f & 31;
      int n = n0 + i;
      float4 t = (n < NN) ? *(const float4*)&x[(size_t)n * DD + c4 * 4]
                          : float4{0.f, 0.f, 0.f, 0.f};
      ushort4v u = { f2bf(t.x), f2bf(t.y), f2bf(t.z), f2bf(t.w) };
      *(ushort4v*)&xl[i * 136 + c4 * 4] = u;
    }
    __syncthreads();

    const int lane = tid & 63, wid = tid >> 6;
    const int rg = wid & 3, cg = wid >> 2;
    const int lr = lane & 15, lg = lane >> 4;

    f32x4 acc0 = {0.f,0.f,0.f,0.f}, acc1 = {0.f,0.f,0.f,0.f};
    f32x4 acc2 = {0.f,0.f,0.f,0.f}, acc3 = {0.f,0.f,0.f,0.f};

    const unsigned short* Ab = &xl[(rg * 16 + lr) * 136];
    const unsigned short* B0 = &WT[(size_t)(cg * 64 +  0 + lr) * DD];
    const unsigned short* B1 = &WT[(size_t)(cg * 64 + 16 + lr) * DD];
    const unsigned short* B2 = &WT[(size_t)(cg * 64 + 32 + lr) * DD];
    const unsigned short* B3 = &WT[(size_t)(cg * 64 + 48 + lr) * DD];

    #pragma unroll
    for (int kk = 0; kk < 4; ++kk) {
      const int kof = kk * 32 + lg * 8;
      short8 a = *(const short8*)(Ab + kof);
      acc0 = __builtin_amdgcn_mfma_f32_16x16x32_bf16(a, *(const short8*)(B0 + kof), acc0, 0, 0, 0);
      acc1 = __builtin_amdgcn_mfma_f32_16x16x32_bf16(a, *(const short8*)(B1 + kof), acc1, 0, 0, 0);
      acc2 = __builtin_amdgcn_mfma_f32_16x16x32_bf16(a, *(const short8*)(B2 + kof), acc2, 0, 0, 0);
      acc3 = __builtin_amdgcn_mfma_f32_16x16x32_bf16(a, *(const short8*)(B3 + kof), acc3, 0, 0, 0);
    }

    const int r0 = rg * 16 + lg * 4;
    const int cb = cg * 64 + lr;
    #pragma unroll
    for (int r = 0; r < 4; ++r) {
      int n = n0 + r0 + r;
      if (n < NN) {
        unsigned short* orow = &o[(size_t)n * DD + cb];
        orow[ 0] = f2bf(acc0[r]);
        orow[16] = f2bf(acc1[r]);
        orow[32] = f2bf(acc2[r]);
        orow[48] = f2bf(acc3[r]);
      }
    }
  }
}

// ---------------------------------------------------------------------------
// Kernel 2: fused edge attention (r12 structure — best measured, 277us),
// 128 dst-sorted edges/block, 512 threads, + XCD-aware bijective block
// swizzle (T1): dst-sorted neighbor blocks share Qh rows and out lines, so
// chunked XCD assignment keeps that working set in ONE per-XCD L2.
// ---------------------------------------------------------------------------
__global__ __launch_bounds__(512, 4) void edge_attn_kernel(
    const unsigned short* __restrict__ kh, const float* __restrict__ e,
    const int* __restrict__ src, const int* __restrict__ dst,
    const int* __restrict__ perm,
    const unsigned short* __restrict__ WkT,
    const unsigned short* __restrict__ Qh, const unsigned short* __restrict__ Vh,
    float* __restrict__ out)
{
  __shared__ __align__(16) unsigned short buf[128 * 136];    // 34816 B
  __shared__ __align__(16) unsigned short vbuf[128 * 136];   // 34816 B
  __shared__ __align__(16) unsigned short pbuf[8 * 16 * 24]; // 6144 B
  __shared__ int s_perm[128], s_src[128], s_dst[128];

  // XCD-aware bijective swizzle (m204): nwg = 6250 = 8*781 + 2
  const int orig = blockIdx.x;
  const int xcd = orig & 7, idx = orig >> 3;
  const int bid = (xcd < 2 ? xcd * 782 : 1564 + (xcd - 2) * 781) + idx;

  const int tid = threadIdx.x;
  const size_t e0 = (size_t)bid * 128;
  const int lane = tid & 63, wid = tid >> 6;
  const int lr = lane & 15, lg = lane >> 4;

  if (tid < 128) {
    int pe = perm[e0 + tid];
    s_perm[tid] = pe;
    s_src[tid] = src[pe];
    s_dst[tid] = dst[pe];
  }
  __syncthreads();

  // ---- batched gather: issue ALL 12 loads, then convert/write ----
  ushort8v vv[4], kv[4];
  float4 ea[4], eb[4];
  #pragma unroll
  for (int p = 0; p < 4; ++p) {
    int f = p * 512 + tid;              // 2048 chunks of 8 cols
    int i2 = f >> 4, c8 = f & 15;
    vv[p] = *(const ushort8v*)&Vh[(size_t)s_src[i2] * DD + c8 * 8];
    kv[p] = *(const ushort8v*)&kh[(size_t)s_src[i2] * DD + c8 * 8];
    const float* ep = &e[(size_t)s_perm[i2] * DD + c8 * 8];
    ea[p] = *(const float4*)ep;
    eb[p] = *(const float4*)(ep + 4);
  }

  // ---- early-issue Q B-frags (fly across staging-convert + phase 1) ----
  const short8 zero8 = {0, 0, 0, 0, 0, 0, 0, 0};
  const int ebase = wid * 16;
  short8 qf[8];
  #pragma unroll
  for (int j = 0; j < 8; ++j) {
    if (lg < 2) {
      int ie = ebase + 2 * j + (lr >> 3);
      qf[j] = *(const short8*)&Qh[(size_t)s_dst[ie] * DD + (lr & 7) * DKK + lg * 8];
    } else qf[j] = zero8;
  }

  #pragma unroll
  for (int p = 0; p < 4; ++p) {
    int f = p * 512 + tid;
    int i2 = f >> 4, c8 = f & 15;
    *(ushort8v*)&vbuf[i2 * 136 + c8 * 8] = vv[p];
    ushort8v o;
    o[0] = f2bf(bf2f(kv[p][0]) + ea[p].x);
    o[1] = f2bf(bf2f(kv[p][1]) + ea[p].y);
    o[2] = f2bf(bf2f(kv[p][2]) + ea[p].z);
    o[3] = f2bf(bf2f(kv[p][3]) + ea[p].w);
    o[4] = f2bf(bf2f(kv[p][4]) + eb[p].x);
    o[5] = f2bf(bf2f(kv[p][5]) + eb[p].y);
    o[6] = f2bf(bf2f(kv[p][6]) + eb[p].z);
    o[7] = f2bf(bf2f(kv[p][7]) + eb[p].w);
    *(ushort8v*)&buf[i2 * 136 + c8 * 8] = o;
  }
  __syncthreads();

  // ---- phase 1: Ke = kke @ Wk, written back IN PLACE over kke ----
  {
    const int rgA = wid & 3, rgB = (wid & 3) + 4, cg = wid >> 2;

    f32x4 aA0 = {0.f,0.f,0.f,0.f}, aA1 = {0.f,0.f,0.f,0.f};
    f32x4 aA2 = {0.f,0.f,0.f,0.f}, aA3 = {0.f,0.f,0.f,0.f};
    f32x4 aB0 = {0.f,0.f,0.f,0.f}, aB1 = {0.f,0.f,0.f,0.f};
    f32x4 aB2 = {0.f,0.f,0.f,0.f}, aB3 = {0.f,0.f,0.f,0.f};

    const unsigned short* AbA = &buf[(rgA * 16 + lr) * 136];
    const unsigned short* AbB = &buf[(rgB * 16 + lr) * 136];
    const unsigned short* B0 = &WkT[(size_t)(cg * 64 +  0 + lr) * DD];
    const unsigned short* B1 = &WkT[(size_t)(cg * 64 + 16 + lr) * DD];
    const unsigned short* B2 = &WkT[(size_t)(cg * 64 + 32 + lr) * DD];
    const unsigned short* B3 = &WkT[(size_t)(cg * 64 + 48 + lr) * DD];

    #pragma unroll
    for (int kk = 0; kk < 4; ++kk) {
      const int kof = kk * 32 + lg * 8;
      short8 b0 = *(const short8*)(B0 + kof);
      short8 b1 = *(const short8*)(B1 + kof);
      short8 b2 = *(const short8*)(B2 + kof);
      short8 b3 = *(const short8*)(B3 + kof);
      short8 fA = *(const short8*)(AbA + kof);
      short8 fB = *(const short8*)(AbB + kof);
      aA0 = __builtin_amdgcn_mfma_f32_16x16x32_bf16(fA, b0, aA0, 0, 0, 0);
      aA1 = __builtin_amdgcn_mfma_f32_16x16x32_bf16(fA, b1, aA1, 0, 0, 0);
      aA2 = __builtin_amdgcn_mfma_f32_16x16x32_bf16(fA, b2, aA2, 0, 0, 0);
      aA3 = __builtin_amdgcn_mfma_f32_16x16x32_bf16(fA, b3, aA3, 0, 0, 0);
      aB0 = __builtin_amdgcn_mfma_f32_16x16x32_bf16(fB, b0, aB0, 0, 0, 0);
      aB1 = __builtin_amdgcn_mfma_f32_16x16x32_bf16(fB, b1, aB1, 0, 0, 0);
      aB2 = __builtin_amdgcn_mfma_f32_16x16x32_bf16(fB, b2, aB2, 0, 0, 0);
      aB3 = __builtin_amdgcn_mfma_f32_16x16x32_bf16(fB, b3, aB3, 0, 0, 0);
    }

    __syncthreads();   // ALL waves done reading kke before any Ke overwrite

    const int rA = rgA * 16 + lg * 4;
    const int rB = rgB * 16 + lg * 4;
    const int cb = cg * 64 + lr;
    #pragma unroll
    for (int r = 0; r < 4; ++r) {
      buf[(rA + r) * 136 + cb +  0] = f2bf(aA0[r]);
      buf[(rA + r) * 136 + cb + 16] = f2bf(aA1[r]);
      buf[(rA + r) * 136 + cb + 32] = f2bf(aA2[r]);
      buf[(rA + r) * 136 + cb + 48] = f2bf(aA3[r]);
      buf[(rB + r) * 136 + cb +  0] = f2bf(aB0[r]);
      buf[(rB + r) * 136 + cb + 16] = f2bf(aB1[r]);
      buf[(rB + r) * 136 + cb + 32] = f2bf(aB2[r]);
      buf[(rB + r) * 136 + cb + 48] = f2bf(aB3[r]);
    }
  }
  __syncthreads();   // Ke ready

  // ---- phase 2: per 2-edge pair, all-MFMA, wave-local (no barriers) ----
  {
    const bool valid = ((lr < 8) == (lg < 2));     // QK C-quadrant mask
    unsigned short* pb = &pbuf[wid * 16 * 24];     // [16][24] per wave

    #pragma unroll
    for (int j = 0; j < 8; ++j) {
      const int iea = ebase + 2 * j, ieb = iea + 1;

      // --- QK: C[r=g-pair][c=h-pair] ---
      short8 af = zero8;
      if (lg < 2) {
        int ie = (lr < 8) ? iea : ieb;
        af = *(const short8*)&buf[ie * 136 + (lr & 7) * DKK + lg * 8];
      }
      f32x4 c = {0.f, 0.f, 0.f, 0.f};
      c = __builtin_amdgcn_mfma_f32_16x16x32_bf16(af, qf[j], c, 0, 0, 0);

      // --- leaky + mask + softmax over g (rows) ---
      float s0, s1, s2, s3;
      {
        float x0 = c[0] * 0.25f, x1 = c[1] * 0.25f;
        float x2 = c[2] * 0.25f, x3 = c[3] * 0.25f;
        x0 = (x0 >= 0.f) ? x0 : 0.01f * x0;
        x1 = (x1 >= 0.f) ? x1 : 0.01f * x1;
        x2 = (x2 >= 0.f) ? x2 : 0.01f * x2;
        x3 = (x3 >= 0.f) ? x3 : 0.01f * x3;
        s0 = valid ? x0 : -1e30f;
        s1 = valid ? x1 : -1e30f;
        s2 = valid ? x2 : -1e30f;
        s3 = valid ? x3 : -1e30f;
      }
      float m = fmaxf(fmaxf(s0, s1), fmaxf(s2, s3));
      m = fmaxf(m, __shfl_xor(m, 16));
      m = fmaxf(m, __shfl_xor(m, 32));
      float p0 = __expf(s0 - m), p1 = __expf(s1 - m);
      float p2 = __expf(s2 - m), p3 = __expf(s3 - m);
      float su = p0 + p1 + p2 + p3;
      su += __shfl_xor(su, 16);
      su += __shfl_xor(su, 32);
      float rs = 1.0f / su;

      // --- P -> pbuf (bf16), row = c-index (h-pair), cols = 4 g's ---
      ushort4v pk = { f2bf(p0 * rs), f2bf(p1 * rs), f2bf(p2 * rs), f2bf(p3 * rs) };
      *(ushort4v*)&pb[lr * 24 + lg * 4] = pk;

      // --- PV: He[r=h-pair][c=d] = mfma(P, V) ---
      short8 pa = zero8;
      if (lg < 2) pa = *(const short8*)&pb[lr * 24 + lg * 8];
      short8 vf = zero8;
      if (lg < 2) {
        const unsigned short* vr = &vbuf[(lg ? ieb : iea) * 136 + lr];
        vf[0] = (short)vr[0 * 16];
        vf[1] = (short)vr[1 * 16];
        vf[2] = (short)vr[2 * 16];
        vf[3] = (short)vr[3 * 16];
        vf[4] = (short)vr[4 * 16];
        vf[5] = (short)vr[5 * 16];
        vf[6] = (short)vr[6 * 16];
        vf[7] = (short)vr[7 * 16];
      }
      f32x4 hc = {0.f, 0.f, 0.f, 0.f};
      hc = __builtin_amdgcn_mfma_f32_16x16x32_bf16(pa, vf, hc, 0, 0, 0);

      // --- He writeback into buf (bf16), rows = lg*4+reg ---
      #pragma unroll
      for (int r = 0; r < 4; ++r) {
        int rr = lg * 4 + r;
        int ie = (rr < 8) ? iea : ieb;
        buf[ie * 136 + (rr & 7) * DKK + lr] = f2bf(hc[r]);
      }
    }
  }

  // ---- wave-local flush: wave w reduces its own 16 edges (no barrier) ----
  {
    const int d2 = lane;                 // col pair 2*d2, 2*d2+1
    const int base = ebase;
    float s0 = 0.0f, s1 = 0.0f;
    int curd = s_dst[base];
    #pragma unroll 8
    for (int j = 0; j < 16; ++j) {
      int i2 = base + j;
      int dn2 = s_dst[i2];
      if (dn2 != curd) {
        atomicAdd(&out[(size_t)curd * DD + d2 * 2],     s0);
        atomicAdd(&out[(size_t)curd * DD + d2 * 2 + 1], s1);
        s0 = 0.0f; s1 = 0.0f;
        curd = dn2;
      }
      unsigned int w = *(const unsigned int*)&buf[i2 * 136 + d2 * 2];
      s0 += bf2f((unsigned short)(w & 0xffff));
      s1 += bf2f((unsigned short)(w >> 16));
    }
    atomicAdd(&out[(size_t)curd * DD + d2 * 2],     s0);
    atomicAdd(&out[(size_t)curd * DD + d2 * 2 + 1], s1);
  }
}

// ---------------------------------------------------------------------------
extern "C" void kernel_launch(void* const* d_in, const int* in_sizes, int n_in,
                              void* d_out, int out_size, void* d_ws, size_t ws_size,
                              hipStream_t stream) {
  const float* q  = (const float*)d_in[0];
  const float* k  = (const float*)d_in[1];
  const float* v  = (const float*)d_in[2];
  const float* e  = (const float*)d_in[3];
  const int*   src = (const int*)d_in[4];
  const int*   dst = (const int*)d_in[5];
  const float* Wq = (const float*)d_in[6];
  const float* Wk = (const float*)d_in[7];
  const float* Wv = (const float*)d_in[8];

  float* out = (float*)d_out;
  char* wsb = (char*)d_ws;
  unsigned short* Qh  = (unsigned short*)wsb;                      // 12.8 MB
  unsigned short* Vh  = Qh + (size_t)NN * DD;                      // 12.8 MB
  unsigned short* kh  = Vh + (size_t)NN * DD;                      // 12.8 MB
  unsigned short* WqT = kh + (size_t)NN * DD;                      // 32 KB each
  unsigned short* WkT = WqT + DD * DD;
  unsigned short* WvT = WkT + DD * DD;
  int* cnt    = (int*)(WvT + DD * DD);                             // [NN]
  int* cur    = cnt + NN;                                          // [NN]
  int* rowptr = cur + NN;                                          // [NN+1]
  int* bsum   = rowptr + NN + 1;                                   // [64]
  int* perm   = bsum + 64;                                         // [EE]

  hipMemsetAsync(d_out, 0, (size_t)NN * DD * sizeof(float), stream);
  hipMemsetAsync(cnt, 0, 2 * NN * sizeof(int), stream);            // cnt + cur

  hist_kernel <<<(EE / 4 + 255) / 256, 256, 0, stream>>>(dst, cnt);
  scan1_kernel<<<SCAN_NB, 256, 0, stream>>>(cnt, bsum);
  scan3_kernel<<<SCAN_NB, 256, 0, stream>>>(cnt, bsum, rowptr);
  fill_kernel <<<(EE / 4 + 255) / 256, 256, 0, stream>>>(dst, rowptr, cur, perm);

  prep_w_kernel<<<3 * DD, DD, 0, stream>>>(Wq, Wk, Wv, WqT, WkT, WvT);
  node_proj_kernel<<<(NN + 63) / 64, 512, 0, stream>>>(q, v, k, WqT, WvT,
                                                       Qh, Vh, kh);
  edge_attn_kernel<<<EE / 128, 512, 0, stream>>>(kh, e, src, dst, perm,
                                                 WkT, Qh, Vh, out);
}